// Round 5
// baseline (432.554 us; speedup 1.0000x reference)
//
#include <hip/hip_runtime.h>
#include <stdint.h>

// ---- problem constants ----
#define M_ROWS   224        // B*N = 32*7
#define K_DIM    49152      // D_MODEL*PATCH_NUMS
#define NCOL     1344       // 4 bands * 336
#define PRED     336
#define S_CHUNKS 32         // 21*32 = 672 blocks, all resident at 3/CU
#define STEPS    48         // K-steps of 32 per chunk: 32*48*32 = 49152

// ws layout: P (bf16 partials, 19.3 MB) at 0; Xbf16 (22 MB) at 32 MB
#define XB_OFFSET (32u * 1024u * 1024u)

typedef __attribute__((ext_vector_type(8))) short short8;
typedef __attribute__((ext_vector_type(4))) float floatx4;

__device__ __forceinline__ uint16_t f32_to_bf16(float f) {
    uint32_t u = __builtin_bit_cast(uint32_t, f);
    uint32_t r = (u + 0x7fffu + ((u >> 16) & 1u)) >> 16;   // RNE
    return (uint16_t)r;
}
__device__ __forceinline__ float bf16_to_f32(uint16_t h) {
    uint32_t u = ((uint32_t)h) << 16;
    return __builtin_bit_cast(float, u);
}
__device__ __forceinline__ uint32_t pack2(float lo, float hi) {
    return (uint32_t)f32_to_bf16(lo) | ((uint32_t)f32_to_bf16(hi) << 16);
}

// ======================= Kernel 0: X fp32 -> bf16 =======================
__global__ __launch_bounds__(256) void cvt_x(
    const float* __restrict__ X, uint16_t* __restrict__ Xb)
{
    const size_t i = ((size_t)blockIdx.x * 256 + threadIdx.x) * 8;
    const float4 a = *(const float4*)(X + i);
    const float4 b = *(const float4*)(X + i + 4);
    uint4 o;
    o.x = pack2(a.x, a.y);
    o.y = pack2(a.z, a.w);
    o.z = pack2(b.x, b.y);
    o.w = pack2(b.z, b.w);
    *(uint4*)(Xb + i) = o;
}

// ======================= Kernel 1: split-K GEMM, ALL-glds staging ====
// Zero VGPR-destination global loads in the K-loop: both X and W are staged
// via global_load_lds, so the compiler has no register-dependency waitcnts
// to insert -- the ONLY VMEM waits are the explicit counted ones.
//   X: 2-deep LDS dbuf (block-shared, 14 KB/buf), issued 1 step ahead.
//   W: 3-deep per-wave-private [32k][16col] fp32 tiles (2 KB/buf), issued
//      2 steps ahead (per-lane gather source; LDS dest lane-linear).
// End-of-step wait: vmcnt(2) = leave only W(st+2) (always the 2 newest ops)
// in flight; drains X(st+1) + W(st+1). lgkmcnt(0) before s_barrier makes the
// 2-buffer X handoff race-free. 672 blocks, 3/CU (LDS 52 KB), XCD swizzle:
// all 21 col-tiles of chunk s on one XCD (4 chunks/XCD, 2.75 MB < 4 MB L2).
__global__ __launch_bounds__(256, 3) void gemm_partial(
    const uint16_t* __restrict__ Xb,  // (224, 49152) bf16
    const float* __restrict__ W,      // (4, 49152, 336) fp32
    uint16_t* __restrict__ P)         // (224, 32, 1344) bf16 partials
{
    __shared__ uint16_t lX[2][14 * 512];   // 2 x 14 KB A-tiles, fragment-ordered
    __shared__ float    lW[4][3][512];     // per-wave 3-deep [32][16] fp32 W tiles

    const int id = blockIdx.x;
    const int g  = id & 7;                   // presumed XCD
    const int q  = id >> 3;                  // 0..83
    const int ct = q % 21;                   // col-tile 0..20
    const int s  = g + 8 * (q / 21);         // K-chunk 0..31, s%8 == XCD

    const int tid  = threadIdx.x;
    const int lane = tid & 63;
    const int w    = tid >> 6;
    const int l15  = lane & 15;
    const int kq   = lane >> 4;
    const int c0w  = ct * 64 + w * 16;
    const int band = c0w / PRED;             // 16 | 336 -> no band straddle
    const int p0   = c0w - band * PRED;

    // W glds source, per lane: instr i covers rows k=i*16+(lane>>2),
    // cols p0+(lane&3)*4 .. +3 (16B contiguous). LDS dest lane-linear ->
    // float idx = i*256 + (lane>>2)*16 + (lane&3)*4  == [k][col] row-major.
    const float* wsrc = W + (size_t)band * ((size_t)K_DIM * PRED)
                          + (size_t)(lane >> 2) * PRED
                          + (size_t)(p0 + (lane & 3) * 4);
    const size_t grow = (size_t)l15 * K_DIM + (size_t)kq * 8;
    const int kbase = s * (STEPS * 32);

    floatx4 acc[14];
    #pragma unroll
    for (int f = 0; f < 14; ++f) acc[f] = (floatx4){0.f, 0.f, 0.f, 0.f};

    // ---- prologue: X(0)->lX[0], W(0)->lW[w][0], W(1)->lW[w][1] ----
    #pragma unroll
    for (int t = 0; t < 4; ++t) {
        const int f = w + 4 * t;
        if (f < 14) {
            const uint16_t* gp = Xb + (size_t)(16 * f) * K_DIM + grow + kbase;
            __builtin_amdgcn_global_load_lds(
                (const __attribute__((address_space(1))) void*)gp,
                (__attribute__((address_space(3))) void*)&lX[0][f * 512],
                16, 0, 0);
        }
    }
    #pragma unroll
    for (int b = 0; b < 2; ++b) {
        #pragma unroll
        for (int i = 0; i < 2; ++i) {
            const float* gp = wsrc + (size_t)(kbase + b * 32 + i * 16) * PRED;
            __builtin_amdgcn_global_load_lds(
                (const __attribute__((address_space(1))) void*)gp,
                (__attribute__((address_space(3))) void*)&lW[w][b][i * 256],
                16, 0, 0);
        }
    }
    asm volatile("s_waitcnt vmcnt(2)" ::: "memory");   // X(0),W(0) done; W(1) in flight
    __builtin_amdgcn_s_barrier();
    __builtin_amdgcn_sched_barrier(0);

    // One step: issue X(ST+1)->lX[XW], W(ST+2)->lW[w][WW] (fire-and-forget),
    // bfrag from lW[w][WR] (8x ds_read_b32 + RNE pack), 14x ds_read_b128 +
    // MFMA from lX[XR], counted wait, barrier.
#define GEMM_STEP(ST, XR, XW, WR, WW, DO_X, DO_W, WAITSTR)                     \
    {                                                                          \
        if (DO_X) {                                                            \
            const int kx = kbase + ((ST) + 1) * 32;                            \
            _Pragma("unroll")                                                  \
            for (int t = 0; t < 4; ++t) {                                      \
                const int f = w + 4 * t;                                       \
                if (f < 14) {                                                  \
                    const uint16_t* gp = Xb + (size_t)(16*f)*K_DIM + grow + kx;\
                    __builtin_amdgcn_global_load_lds(                          \
                        (const __attribute__((address_space(1))) void*)gp,     \
                        (__attribute__((address_space(3))) void*)&lX[XW][f*512],\
                        16, 0, 0);                                             \
                }                                                              \
            }                                                                  \
        }                                                                      \
        if (DO_W) {                                                            \
            const int kw2 = kbase + ((ST) + 2) * 32;                           \
            _Pragma("unroll")                                                  \
            for (int i = 0; i < 2; ++i) {                                      \
                const float* gp = wsrc + (size_t)(kw2 + i * 16) * PRED;        \
                __builtin_amdgcn_global_load_lds(                              \
                    (const __attribute__((address_space(1))) void*)gp,         \
                    (__attribute__((address_space(3))) void*)&lW[w][WW][i*256],\
                    16, 0, 0);                                                 \
            }                                                                  \
        }                                                                      \
        float wv[8];                                                           \
        _Pragma("unroll")                                                      \
        for (int j = 0; j < 8; ++j)                                            \
            wv[j] = lW[w][WR][(kq * 8 + j) * 16 + l15];                        \
        short8 bfrag;                                                          \
        _Pragma("unroll")                                                      \
        for (int j = 0; j < 4; ++j)                                            \
            ((uint32_t*)&bfrag)[j] = pack2(wv[2 * j], wv[2 * j + 1]);          \
        _Pragma("unroll")                                                      \
        for (int f = 0; f < 14; ++f) {                                         \
            short8 afrag = *(const short8*)&lX[XR][f * 512 + lane * 8];        \
            acc[f] = __builtin_amdgcn_mfma_f32_16x16x32_bf16(                  \
                afrag, bfrag, acc[f], 0, 0, 0);                                \
        }                                                                      \
        asm volatile("s_waitcnt " WAITSTR " lgkmcnt(0)" ::: "memory");         \
        __builtin_amdgcn_s_barrier();                                          \
        __builtin_amdgcn_sched_barrier(0);                                     \
    }

    // Main loop: st multiple of 6 -> (st+o)%2 == o%2, (st+o)%3 == o%3:
    // all buffer indices compile-time; no conditionals (st+2 <= 43 < 48).
    for (int st = 0; st < 42; st += 6) {
        GEMM_STEP(st + 0, 0, 1, 0, 2, 1, 1, "vmcnt(2)")
        GEMM_STEP(st + 1, 1, 0, 1, 0, 1, 1, "vmcnt(2)")
        GEMM_STEP(st + 2, 0, 1, 2, 1, 1, 1, "vmcnt(2)")
        GEMM_STEP(st + 3, 1, 0, 0, 2, 1, 1, "vmcnt(2)")
        GEMM_STEP(st + 4, 0, 1, 1, 0, 1, 1, "vmcnt(2)")
        GEMM_STEP(st + 5, 1, 0, 2, 1, 1, 1, "vmcnt(2)")
    }
    // Tail: steps 42..47 peeled with compile-time flags/waits.
    GEMM_STEP(42, 0, 1, 0, 2, 1, 1, "vmcnt(2)")
    GEMM_STEP(43, 1, 0, 1, 0, 1, 1, "vmcnt(2)")
    GEMM_STEP(44, 0, 1, 2, 1, 1, 1, "vmcnt(2)")
    GEMM_STEP(45, 1, 0, 0, 2, 1, 1, "vmcnt(2)")   // issues W(47)
    GEMM_STEP(46, 0, 1, 1, 0, 1, 0, "vmcnt(0)")   // issues X(47); drain all
    GEMM_STEP(47, 1, 0, 2, 1, 0, 0, "vmcnt(0)")
#undef GEMM_STEP

    // ---- write bf16 partials: C/D layout col=lane&15, row=kq*4+reg ----
    const int col = c0w + l15;
    #pragma unroll
    for (int f = 0; f < 14; ++f) {
        #pragma unroll
        for (int r = 0; r < 4; ++r) {
            const int m = 16 * f + kq * 4 + r;
            P[((size_t)m * S_CHUNKS + s) * NCOL + col] = f32_to_bf16(acc[f][r]);
        }
    }
}

// ======================= Kernel 2: partial reduce + bias + iSWT =======================
__device__ const float REC_LO[8] = {
     0.23037781330885523f,  0.7148465705525415f,   0.6308807679295904f,
    -0.02798376941698385f, -0.18703481171888114f,  0.030841381835986965f,
     0.032883011666982945f, -0.010597401784997278f };
__device__ const float REC_HI[8] = {
     0.010597401784997278f, 0.032883011666982945f, -0.030841381835986965f,
    -0.18703481171888114f,  0.02798376941698385f,   0.6308807679295904f,
    -0.7148465705525415f,   0.23037781330885523f };

__global__ __launch_bounds__(1024) void reduce_iswt(
    const uint16_t* __restrict__ P,    // (224, 32, 1344) bf16
    const float* __restrict__ bias,    // (4, 336) flat == flat col
    float* __restrict__ out)           // (224, 336)
{
    __shared__ float coeff[NCOL];
    __shared__ float buf[2][PRED];

    const int row = blockIdx.x;
    const int tid = threadIdx.x;
    const uint32_t* pr = (const uint32_t*)(P + (size_t)row * S_CHUNKS * NCOL);

    if (tid < NCOL / 2) {
        float a0 = 0.f, a1 = 0.f;
        #pragma unroll 8
        for (int s = 0; s < S_CHUNKS; ++s) {
            const uint32_t v = pr[s * (NCOL / 2) + tid];
            a0 += bf16_to_f32((uint16_t)(v & 0xffff));
            a1 += bf16_to_f32((uint16_t)(v >> 16));
        }
        coeff[2 * tid]     = a0 + bias[2 * tid];
        coeff[2 * tid + 1] = a1 + bias[2 * tid + 1];
    }
    __syncthreads();

    if (tid < PRED) buf[0][tid] = coeff[tid];   // band 0 = cA
    __syncthreads();

    int curb = 0;
    for (int j = 3; j >= 1; --j) {
        const int step = 1 << (j - 1);              // 4, 2, 1
        const int M    = PRED / step;               // 84, 168, 336
        const float* cd  = &coeff[(4 - j) * PRED];  // cD3, cD2, cD1
        const float* cur = buf[curb];
        float* nxt       = buf[curb ^ 1];
        if (tid < PRED) {
            const int t = tid;
            const int sidx = t & (step - 1);
            const int m = t / step;
            const int mm1 = (m == 0) ? (M - 1) : (m - 1);
            float x1 = 0.f, x2 = 0.f;
            #pragma unroll
            for (int k = 0; k < 8; ++k) {
                int i1 = m + 3 - k;  if (i1 < 0) i1 += M; else if (i1 >= M) i1 -= M;
                if ((i1 & 1) == 0) {
                    const int pos = i1 * step + sidx;
                    x1 += cur[pos] * REC_LO[k] + cd[pos] * REC_HI[k];
                }
                int i2 = mm1 + 3 - k;  if (i2 < 0) i2 += M; else if (i2 >= M) i2 -= M;
                if ((i2 & 1) == 0) {
                    const int pos = (i2 + 1) * step + sidx;
                    x2 += cur[pos] * REC_LO[k] + cd[pos] * REC_HI[k];
                }
            }
            nxt[t] = 0.5f * (x1 + x2);
        }
        __syncthreads();
        curb ^= 1;
    }

    if (tid < PRED) out[(size_t)row * PRED + tid] = buf[curb][tid];
}

// ======================= launch =======================
extern "C" void kernel_launch(void* const* d_in, const int* in_sizes, int n_in,
                              void* d_out, int out_size, void* d_ws, size_t ws_size,
                              hipStream_t stream) {
    const float* X    = (const float*)d_in[0];   // (224, 49152)
    const float* W    = (const float*)d_in[1];   // (4, 49152, 336)
    const float* bias = (const float*)d_in[2];   // (4, 336)
    float* out        = (float*)d_out;           // (224, 336)
    uint16_t* P       = (uint16_t*)d_ws;                          // 19.3 MB partials
    uint16_t* Xb      = (uint16_t*)((char*)d_ws + XB_OFFSET);     // 22 MB bf16 X

    cvt_x       <<<5376, 256, 0, stream>>>(X, Xb);
    gemm_partial<<<21 * S_CHUNKS, 256, 0, stream>>>(Xb, W, P);
    reduce_iswt <<<M_ROWS, 1024, 0, stream>>>(P, bias, out);
}

// Round 6
// 428.436 us; speedup vs baseline: 1.0096x; 1.0096x over previous
//
#include <hip/hip_runtime.h>
#include <stdint.h>

// ---- problem constants ----
#define M_ROWS   224        // B*N = 32*7
#define K_DIM    49152      // D_MODEL*PATCH_NUMS
#define NCOL     1344       // 4 bands * 336
#define PRED     336
#define S_CHUNKS 48         // 21*48 = 1008 blocks = 3.94/CU
#define STEPS    32         // K-steps of 32 per chunk

// ws layout: P (bf16 partials, 29 MB) at 0; Xbf16 (22 MB) at 32 MB
#define XB_OFFSET (32u * 1024u * 1024u)

typedef __attribute__((ext_vector_type(8))) short short8;
typedef __attribute__((ext_vector_type(4))) float floatx4;

__device__ __forceinline__ uint16_t f32_to_bf16(float f) {
    uint32_t u = __builtin_bit_cast(uint32_t, f);
    uint32_t r = (u + 0x7fffu + ((u >> 16) & 1u)) >> 16;   // RNE
    return (uint16_t)r;
}
__device__ __forceinline__ float bf16_to_f32(uint16_t h) {
    uint32_t u = ((uint32_t)h) << 16;
    return __builtin_bit_cast(float, u);
}
__device__ __forceinline__ uint32_t pack2(float lo, float hi) {
    return (uint32_t)f32_to_bf16(lo) | ((uint32_t)f32_to_bf16(hi) << 16);
}

// ======================= Kernel 0: X fp32 -> bf16 =======================
__global__ __launch_bounds__(256) void cvt_x(
    const float* __restrict__ X, uint16_t* __restrict__ Xb)
{
    const size_t i = ((size_t)blockIdx.x * 256 + threadIdx.x) * 8;
    const float4 a = *(const float4*)(X + i);
    const float4 b = *(const float4*)(X + i + 4);
    uint4 o;
    o.x = pack2(a.x, a.y);
    o.y = pack2(a.z, a.w);
    o.z = pack2(b.x, b.y);
    o.w = pack2(b.z, b.w);
    *(uint4*)(Xb + i) = o;
}

// ======================= Kernel 1: split-K GEMM, 3-buf X pipeline ====
// r0/r4/r5 all plateau at gemm ~148us with X staged 1 step ahead (the shared
// invariant). This version pipelines X glds TWO steps ahead through 3 LDS
// buffers: X(st) is issued at step st-2, so each glds gets ~2 full step-times
// to complete before its counted drain at end of step st-1. W: 2-deep reg
// ping-pong (wA/wB, packed before reload -> compiler waits are 2 steps slack).
// End-of-step wait vmcnt(11): per-wave in-step VMEM issue is 11 or 12
// (3-4 X glds + 8 W dwords), so vmcnt(11) drains every pre-step op for all
// waves while leaving this step's prefetches in flight. lgkmcnt(0) before
// s_barrier keeps the 3-buffer handoff race-free (reads of buf[st%3] done
// before st's barrier; writes to buf[(st+2)%3] only touch a buffer last read
// at st-1). 1008 blocks, 3/CU (LDS 42 KB), XCD swizzle: all 21 col-tiles of
// chunk s on one XCD -> X slice HBM-read once per XCD, L2-served 21x.
__global__ __launch_bounds__(256, 3) void gemm_partial(
    const uint16_t* __restrict__ Xb,  // (224, 49152) bf16
    const float* __restrict__ W,      // (4, 49152, 336) fp32
    uint16_t* __restrict__ P)         // (224, 48, 1344) bf16 partials
{
    __shared__ uint16_t lX[3][14 * 512];     // 3 x 14 KB, fragment-ordered

    const int id = blockIdx.x;
    const int g  = id & 7;                   // presumed XCD
    const int q  = id >> 3;                  // 0..125
    const int ct = q % 21;                   // col-tile 0..20
    const int s  = g + 8 * (q / 21);         // K-chunk 0..47, s%8 == XCD

    const int tid  = threadIdx.x;
    const int lane = tid & 63;
    const int w    = tid >> 6;
    const int l15  = lane & 15;
    const int kq   = lane >> 4;
    const int c0w  = ct * 64 + w * 16;
    const int band = c0w / PRED;             // 16 | 336 -> no band straddle
    const int p0   = c0w - band * PRED;

    const float* wbase = W + (size_t)band * ((size_t)K_DIM * PRED)
                           + (size_t)(kq * 8) * PRED
                           + (size_t)(p0 + l15);
    const size_t grow = (size_t)l15 * K_DIM + (size_t)kq * 8;
    const int kbase = s * (STEPS * 32);

    floatx4 acc[14];
    #pragma unroll
    for (int f = 0; f < 14; ++f) acc[f] = (floatx4){0.f, 0.f, 0.f, 0.f};

    float wA[8], wB[8];                      // 2-deep W ping-pong

    // ---- prologue: X(0)->buf0, X(1)->buf1, W(0)->wA, W(1)->wB ----
    #pragma unroll
    for (int b = 0; b < 2; ++b) {
        #pragma unroll
        for (int t = 0; t < 4; ++t) {
            const int f = w + 4 * t;
            if (f < 14) {
                const uint16_t* gp = Xb + (size_t)(16 * f) * K_DIM + grow
                                        + kbase + b * 32;
                __builtin_amdgcn_global_load_lds(
                    (const __attribute__((address_space(1))) void*)gp,
                    (__attribute__((address_space(3))) void*)&lX[b][f * 512],
                    16, 0, 0);
            }
        }
    }
    #pragma unroll
    for (int j = 0; j < 8; ++j) wA[j] = wbase[(size_t)(kbase + j) * PRED];
    #pragma unroll
    for (int j = 0; j < 8; ++j) wB[j] = wbase[(size_t)(kbase + 32 + j) * PRED];
    asm volatile("s_waitcnt vmcnt(0)" ::: "memory");   // one-time full drain
    __builtin_amdgcn_s_barrier();
    __builtin_amdgcn_sched_barrier(0);

    // One step: issue X(ST+2)->lX[XW] | pack bfrag(WREG) | reload WREG<-W(ST+2)
    //           | 14x ds_read_b128 + MFMA from lX[XR] | vmcnt(11) lgkm(0) bar
#define GEMM_STEP(ST, XR, XW, WREG, DO_PRE, WAITSTR)                           \
    {                                                                          \
        if (DO_PRE) {                                                          \
            const int kx = kbase + ((ST) + 2) * 32;                            \
            _Pragma("unroll")                                                  \
            for (int t = 0; t < 4; ++t) {                                      \
                const int f = w + 4 * t;                                       \
                if (f < 14) {                                                  \
                    const uint16_t* gp = Xb + (size_t)(16*f)*K_DIM + grow + kx;\
                    __builtin_amdgcn_global_load_lds(                          \
                        (const __attribute__((address_space(1))) void*)gp,     \
                        (__attribute__((address_space(3))) void*)&lX[XW][f*512],\
                        16, 0, 0);                                             \
                }                                                              \
            }                                                                  \
        }                                                                      \
        short8 bfrag;                                                          \
        _Pragma("unroll")                                                      \
        for (int j = 0; j < 4; ++j)                                            \
            ((uint32_t*)&bfrag)[j] = pack2(WREG[2*j], WREG[2*j+1]);            \
        if (DO_PRE) {                                                          \
            const int kw2 = kbase + ((ST) + 2) * 32;                           \
            _Pragma("unroll")                                                  \
            for (int j = 0; j < 8; ++j)                                        \
                WREG[j] = wbase[(size_t)(kw2 + j) * PRED];                     \
        }                                                                      \
        _Pragma("unroll")                                                      \
        for (int f = 0; f < 14; ++f) {                                         \
            short8 afrag = *(const short8*)&lX[XR][f * 512 + lane * 8];        \
            acc[f] = __builtin_amdgcn_mfma_f32_16x16x32_bf16(                  \
                afrag, bfrag, acc[f], 0, 0, 0);                                \
        }                                                                      \
        asm volatile("s_waitcnt " WAITSTR " lgkmcnt(0)" ::: "memory");         \
        __builtin_amdgcn_s_barrier();                                          \
        __builtin_amdgcn_sched_barrier(0);                                     \
    }

    // Main loop: st multiple of 6 -> (st+o)%3 == o%3, (st+o)%2 == o%2:
    // all buffer/reg indices compile-time. Steps 0..29 all prefetch st+2<=31.
    for (int st = 0; st < 30; st += 6) {
        GEMM_STEP(st + 0, 0, 2, wA, 1, "vmcnt(11)")
        GEMM_STEP(st + 1, 1, 0, wB, 1, "vmcnt(11)")
        GEMM_STEP(st + 2, 2, 1, wA, 1, "vmcnt(11)")
        GEMM_STEP(st + 3, 0, 2, wB, 1, "vmcnt(11)")
        GEMM_STEP(st + 4, 1, 0, wA, 1, "vmcnt(11)")
        GEMM_STEP(st + 5, 2, 1, wB, 1, "vmcnt(11)")
    }
    // Tail: steps 30, 31 -- no prefetch; drain everything once.
    GEMM_STEP(30, 0, 2, wA, 0, "vmcnt(0)")
    GEMM_STEP(31, 1, 0, wB, 0, "vmcnt(0)")
#undef GEMM_STEP

    // ---- write bf16 partials: C/D layout col=lane&15, row=kq*4+reg ----
    const int col = c0w + l15;
    #pragma unroll
    for (int f = 0; f < 14; ++f) {
        #pragma unroll
        for (int r = 0; r < 4; ++r) {
            const int m = 16 * f + kq * 4 + r;
            P[((size_t)m * S_CHUNKS + s) * NCOL + col] = f32_to_bf16(acc[f][r]);
        }
    }
}

// ======================= Kernel 2: partial reduce + bias + iSWT =======================
__device__ const float REC_LO[8] = {
     0.23037781330885523f,  0.7148465705525415f,   0.6308807679295904f,
    -0.02798376941698385f, -0.18703481171888114f,  0.030841381835986965f,
     0.032883011666982945f, -0.010597401784997278f };
__device__ const float REC_HI[8] = {
     0.010597401784997278f, 0.032883011666982945f, -0.030841381835986965f,
    -0.18703481171888114f,  0.02798376941698385f,   0.6308807679295904f,
    -0.7148465705525415f,   0.23037781330885523f };

__global__ __launch_bounds__(1024) void reduce_iswt(
    const uint16_t* __restrict__ P,    // (224, 48, 1344) bf16
    const float* __restrict__ bias,    // (4, 336) flat == flat col
    float* __restrict__ out)           // (224, 336)
{
    __shared__ float coeff[NCOL];
    __shared__ float buf[2][PRED];

    const int row = blockIdx.x;
    const int tid = threadIdx.x;
    const uint32_t* pr = (const uint32_t*)(P + (size_t)row * S_CHUNKS * NCOL);

    if (tid < NCOL / 2) {
        float a0 = 0.f, a1 = 0.f;
        #pragma unroll 8
        for (int s = 0; s < S_CHUNKS; ++s) {
            const uint32_t v = pr[s * (NCOL / 2) + tid];
            a0 += bf16_to_f32((uint16_t)(v & 0xffff));
            a1 += bf16_to_f32((uint16_t)(v >> 16));
        }
        coeff[2 * tid]     = a0 + bias[2 * tid];
        coeff[2 * tid + 1] = a1 + bias[2 * tid + 1];
    }
    __syncthreads();

    if (tid < PRED) buf[0][tid] = coeff[tid];   // band 0 = cA
    __syncthreads();

    int curb = 0;
    for (int j = 3; j >= 1; --j) {
        const int step = 1 << (j - 1);              // 4, 2, 1
        const int M    = PRED / step;               // 84, 168, 336
        const float* cd  = &coeff[(4 - j) * PRED];  // cD3, cD2, cD1
        const float* cur = buf[curb];
        float* nxt       = buf[curb ^ 1];
        if (tid < PRED) {
            const int t = tid;
            const int sidx = t & (step - 1);
            const int m = t / step;
            const int mm1 = (m == 0) ? (M - 1) : (m - 1);
            float x1 = 0.f, x2 = 0.f;
            #pragma unroll
            for (int k = 0; k < 8; ++k) {
                int i1 = m + 3 - k;  if (i1 < 0) i1 += M; else if (i1 >= M) i1 -= M;
                if ((i1 & 1) == 0) {
                    const int pos = i1 * step + sidx;
                    x1 += cur[pos] * REC_LO[k] + cd[pos] * REC_HI[k];
                }
                int i2 = mm1 + 3 - k;  if (i2 < 0) i2 += M; else if (i2 >= M) i2 -= M;
                if ((i2 & 1) == 0) {
                    const int pos = (i2 + 1) * step + sidx;
                    x2 += cur[pos] * REC_LO[k] + cd[pos] * REC_HI[k];
                }
            }
            nxt[t] = 0.5f * (x1 + x2);
        }
        __syncthreads();
        curb ^= 1;
    }

    if (tid < PRED) out[(size_t)row * PRED + tid] = buf[curb][tid];
}

// ======================= launch =======================
extern "C" void kernel_launch(void* const* d_in, const int* in_sizes, int n_in,
                              void* d_out, int out_size, void* d_ws, size_t ws_size,
                              hipStream_t stream) {
    const float* X    = (const float*)d_in[0];   // (224, 49152)
    const float* W    = (const float*)d_in[1];   // (4, 49152, 336)
    const float* bias = (const float*)d_in[2];   // (4, 336)
    float* out        = (float*)d_out;           // (224, 336)
    uint16_t* P       = (uint16_t*)d_ws;                          // 29 MB partials
    uint16_t* Xb      = (uint16_t*)((char*)d_ws + XB_OFFSET);     // 22 MB bf16 X

    cvt_x       <<<5376, 256, 0, stream>>>(X, Xb);
    gemm_partial<<<21 * S_CHUNKS, 256, 0, stream>>>(Xb, W, P);
    reduce_iswt <<<M_ROWS, 1024, 0, stream>>>(P, bias, out);
}

// Round 7
// 425.738 us; speedup vs baseline: 1.0160x; 1.0063x over previous
//
#include <hip/hip_runtime.h>
#include <stdint.h>

// ---- problem constants ----
#define M_ROWS   224        // B*N = 32*7
#define K_DIM    49152      // D_MODEL*PATCH_NUMS
#define NCOL     1344       // 4 bands * 336
#define PRED     336
#define S_CHUNKS 48         // K-chunks; P layout (224, 48, 1344)
#define STEPS    32         // K-steps of 32 per chunk
#define CTILES   14         // 1344/96 col-tiles

// ws layout: P (bf16 partials, 29 MB) at 0; Xbf16 (22 MB) at 32 MB
#define XB_OFFSET (32u * 1024u * 1024u)

typedef __attribute__((ext_vector_type(8))) short short8;
typedef __attribute__((ext_vector_type(4))) float floatx4;

__device__ __forceinline__ uint16_t f32_to_bf16(float f) {
    uint32_t u = __builtin_bit_cast(uint32_t, f);
    uint32_t r = (u + 0x7fffu + ((u >> 16) & 1u)) >> 16;   // RNE
    return (uint16_t)r;
}
__device__ __forceinline__ float bf16_to_f32(uint16_t h) {
    uint32_t u = ((uint32_t)h) << 16;
    return __builtin_bit_cast(float, u);
}
__device__ __forceinline__ uint32_t pack2(float lo, float hi) {
    return (uint32_t)f32_to_bf16(lo) | ((uint32_t)f32_to_bf16(hi) << 16);
}

// ======================= Kernel 0: X fp32 -> bf16 =======================
__global__ __launch_bounds__(256) void cvt_x(
    const float* __restrict__ X, uint16_t* __restrict__ Xb)
{
    const size_t i = ((size_t)blockIdx.x * 256 + threadIdx.x) * 8;
    const float4 a = *(const float4*)(X + i);
    const float4 b = *(const float4*)(X + i + 4);
    uint4 o;
    o.x = pack2(a.x, a.y);
    o.y = pack2(a.z, a.w);
    o.z = pack2(b.x, b.y);
    o.w = pack2(b.z, b.w);
    *(uint4*)(Xb + i) = o;
}

// ======================= Kernel 1: split-K GEMM, 224x96 tile, 3 waves ====
// GEOMETRY change (r0-r6 all ~145us at 126 block-steps/CU, ~2.8k cy/step
// invariant): each wave now owns TWO 16-col B-fragments, so every A-frag
// ds_read_b128 feeds 2 MFMAs. Block = 224x96, 3 waves, grid 14x48 = 672
// -> 84 block-steps/CU (-33%) at (predicted) similar per-step cost.
// All fragment layouts identical to the proven kernel; 16-col fragments
// never straddle a band (336 = 21*16), so band/p0 stay per-wave scalars
// (two of them). Schedule = r6's: 3-buf X glds 2 steps ahead, W 2-deep
// reg ping-pong, end-of-step s_waitcnt vmcnt(20) lgkmcnt(0) (per-wave
// in-step issue = 4/5 glds + 16 W dwords -> keeps this step's prefetches
// in flight, drains X(st+1)). XCD swizzle: 14 col-tiles of chunk s land
// on one XCD -> X slice HBM-read once per XCD, L2-served 14x.
__global__ __launch_bounds__(192, 2) void gemm_partial(
    const uint16_t* __restrict__ Xb,  // (224, 49152) bf16
    const float* __restrict__ W,      // (4, 49152, 336) fp32
    uint16_t* __restrict__ P)         // (224, 48, 1344) bf16 partials
{
    __shared__ uint16_t lX[3][14 * 512];     // 3 x 14 KB, fragment-ordered

    const int id = blockIdx.x;
    const int g  = id & 7;                   // presumed XCD
    const int q  = id >> 3;                  // 0..83
    const int ct = q % CTILES;               // col-tile 0..13
    const int s  = g + 8 * (q / CTILES);     // K-chunk 0..47, s%8 == XCD

    const int tid  = threadIdx.x;
    const int lane = tid & 63;
    const int w    = tid >> 6;               // wave 0..2
    const int l15  = lane & 15;
    const int kq   = lane >> 4;

    // two 16-col fragments per wave; 16 | 336 -> no band straddle per frag
    const int c0w   = ct * 96 + w * 32;      // frag 0 cols [c0w, c0w+16)
    const int c1w   = c0w + 16;              // frag 1 cols [c1w, c1w+16)
    const int band0 = c0w / PRED, band1 = c1w / PRED;
    const int p00   = c0w - band0 * PRED;
    const int p01   = c1w - band1 * PRED;

    const float* wbase0 = W + (size_t)band0 * ((size_t)K_DIM * PRED)
                            + (size_t)(kq * 8) * PRED + (size_t)(p00 + l15);
    const float* wbase1 = W + (size_t)band1 * ((size_t)K_DIM * PRED)
                            + (size_t)(kq * 8) * PRED + (size_t)(p01 + l15);
    const size_t grow = (size_t)l15 * K_DIM + (size_t)kq * 8;
    const int kbase = s * (STEPS * 32);

    floatx4 acc0[14], acc1[14];
    #pragma unroll
    for (int f = 0; f < 14; ++f) {
        acc0[f] = (floatx4){0.f, 0.f, 0.f, 0.f};
        acc1[f] = (floatx4){0.f, 0.f, 0.f, 0.f};
    }

    float wA0[8], wA1[8], wB0[8], wB1[8];    // 2-deep W ping-pong x 2 frags

    // ---- prologue: X(0)->buf0, X(1)->buf1, W(0)->wA*, W(1)->wB* ----
    #pragma unroll
    for (int b = 0; b < 2; ++b) {
        #pragma unroll
        for (int t = 0; t < 5; ++t) {
            const int f = w + 3 * t;         // 3 waves cover 14 frags (5/5/4)
            if (f < 14) {
                const uint16_t* gp = Xb + (size_t)(16 * f) * K_DIM + grow
                                        + kbase + b * 32;
                __builtin_amdgcn_global_load_lds(
                    (const __attribute__((address_space(1))) void*)gp,
                    (__attribute__((address_space(3))) void*)&lX[b][f * 512],
                    16, 0, 0);
            }
        }
    }
    #pragma unroll
    for (int j = 0; j < 8; ++j) {
        wA0[j] = wbase0[(size_t)(kbase + j) * PRED];
        wA1[j] = wbase1[(size_t)(kbase + j) * PRED];
    }
    #pragma unroll
    for (int j = 0; j < 8; ++j) {
        wB0[j] = wbase0[(size_t)(kbase + 32 + j) * PRED];
        wB1[j] = wbase1[(size_t)(kbase + 32 + j) * PRED];
    }
    asm volatile("s_waitcnt vmcnt(0)" ::: "memory");   // one-time full drain
    __builtin_amdgcn_s_barrier();
    __builtin_amdgcn_sched_barrier(0);

    // One step: issue X(ST+2)->lX[XW] | pack bfrag0/1 | reload WREGs<-W(ST+2)
    //           | 14x { ds_read_b128; MFMA x2 } | vmcnt(20) lgkm(0) barrier
#define GEMM_STEP(ST, XR, XW, WR0, WR1, DO_PRE, WAITSTR)                       \
    {                                                                          \
        if (DO_PRE) {                                                          \
            const int kx = kbase + ((ST) + 2) * 32;                            \
            _Pragma("unroll")                                                  \
            for (int t = 0; t < 5; ++t) {                                      \
                const int f = w + 3 * t;                                       \
                if (f < 14) {                                                  \
                    const uint16_t* gp = Xb + (size_t)(16*f)*K_DIM + grow + kx;\
                    __builtin_amdgcn_global_load_lds(                          \
                        (const __attribute__((address_space(1))) void*)gp,     \
                        (__attribute__((address_space(3))) void*)&lX[XW][f*512],\
                        16, 0, 0);                                             \
                }                                                              \
            }                                                                  \
        }                                                                      \
        short8 bfrag0, bfrag1;                                                 \
        _Pragma("unroll")                                                      \
        for (int j = 0; j < 4; ++j) {                                          \
            ((uint32_t*)&bfrag0)[j] = pack2(WR0[2*j], WR0[2*j+1]);             \
            ((uint32_t*)&bfrag1)[j] = pack2(WR1[2*j], WR1[2*j+1]);             \
        }                                                                      \
        if (DO_PRE) {                                                          \
            const int kw2 = kbase + ((ST) + 2) * 32;                           \
            _Pragma("unroll")                                                  \
            for (int j = 0; j < 8; ++j) {                                      \
                WR0[j] = wbase0[(size_t)(kw2 + j) * PRED];                     \
                WR1[j] = wbase1[(size_t)(kw2 + j) * PRED];                     \
            }                                                                  \
        }                                                                      \
        _Pragma("unroll")                                                      \
        for (int f = 0; f < 14; ++f) {                                         \
            short8 afrag = *(const short8*)&lX[XR][f * 512 + lane * 8];        \
            acc0[f] = __builtin_amdgcn_mfma_f32_16x16x32_bf16(                 \
                afrag, bfrag0, acc0[f], 0, 0, 0);                              \
            acc1[f] = __builtin_amdgcn_mfma_f32_16x16x32_bf16(                 \
                afrag, bfrag1, acc1[f], 0, 0, 0);                              \
        }                                                                      \
        asm volatile("s_waitcnt " WAITSTR " lgkmcnt(0)" ::: "memory");         \
        __builtin_amdgcn_s_barrier();                                          \
        __builtin_amdgcn_sched_barrier(0);                                     \
    }

    // Main loop: st multiple of 6 -> (st+o)%3 == o%3, (st+o)%2 == o%2:
    // all buffer/reg indices compile-time. Steps 0..29 prefetch st+2 <= 31.
    for (int st = 0; st < 30; st += 6) {
        GEMM_STEP(st + 0, 0, 2, wA0, wA1, 1, "vmcnt(20)")
        GEMM_STEP(st + 1, 1, 0, wB0, wB1, 1, "vmcnt(20)")
        GEMM_STEP(st + 2, 2, 1, wA0, wA1, 1, "vmcnt(20)")
        GEMM_STEP(st + 3, 0, 2, wB0, wB1, 1, "vmcnt(20)")
        GEMM_STEP(st + 4, 1, 0, wA0, wA1, 1, "vmcnt(20)")
        GEMM_STEP(st + 5, 2, 1, wB0, wB1, 1, "vmcnt(20)")
    }
    // Tail: steps 30, 31 -- no prefetch; full drain.
    GEMM_STEP(30, 0, 2, wA0, wA1, 0, "vmcnt(0)")
    GEMM_STEP(31, 1, 0, wB0, wB1, 0, "vmcnt(0)")
#undef GEMM_STEP

    // ---- write bf16 partials: C/D layout col=lane&15, row=kq*4+reg ----
    const int col0 = c0w + l15;
    const int col1 = c1w + l15;
    #pragma unroll
    for (int f = 0; f < 14; ++f) {
        #pragma unroll
        for (int r = 0; r < 4; ++r) {
            const int m = 16 * f + kq * 4 + r;
            const size_t base = ((size_t)m * S_CHUNKS + s) * NCOL;
            P[base + col0] = f32_to_bf16(acc0[f][r]);
            P[base + col1] = f32_to_bf16(acc1[f][r]);
        }
    }
}

// ======================= Kernel 2: partial reduce + bias + iSWT =======================
__device__ const float REC_LO[8] = {
     0.23037781330885523f,  0.7148465705525415f,   0.6308807679295904f,
    -0.02798376941698385f, -0.18703481171888114f,  0.030841381835986965f,
     0.032883011666982945f, -0.010597401784997278f };
__device__ const float REC_HI[8] = {
     0.010597401784997278f, 0.032883011666982945f, -0.030841381835986965f,
    -0.18703481171888114f,  0.02798376941698385f,   0.6308807679295904f,
    -0.7148465705525415f,   0.23037781330885523f };

__global__ __launch_bounds__(1024) void reduce_iswt(
    const uint16_t* __restrict__ P,    // (224, 48, 1344) bf16
    const float* __restrict__ bias,    // (4, 336) flat == flat col
    float* __restrict__ out)           // (224, 336)
{
    __shared__ float coeff[NCOL];
    __shared__ float buf[2][PRED];

    const int row = blockIdx.x;
    const int tid = threadIdx.x;
    const uint32_t* pr = (const uint32_t*)(P + (size_t)row * S_CHUNKS * NCOL);

    if (tid < NCOL / 2) {
        float a0 = 0.f, a1 = 0.f;
        #pragma unroll 8
        for (int s = 0; s < S_CHUNKS; ++s) {
            const uint32_t v = pr[s * (NCOL / 2) + tid];
            a0 += bf16_to_f32((uint16_t)(v & 0xffff));
            a1 += bf16_to_f32((uint16_t)(v >> 16));
        }
        coeff[2 * tid]     = a0 + bias[2 * tid];
        coeff[2 * tid + 1] = a1 + bias[2 * tid + 1];
    }
    __syncthreads();

    if (tid < PRED) buf[0][tid] = coeff[tid];   // band 0 = cA
    __syncthreads();

    int curb = 0;
    for (int j = 3; j >= 1; --j) {
        const int step = 1 << (j - 1);              // 4, 2, 1
        const int M    = PRED / step;               // 84, 168, 336
        const float* cd  = &coeff[(4 - j) * PRED];  // cD3, cD2, cD1
        const float* cur = buf[curb];
        float* nxt       = buf[curb ^ 1];
        if (tid < PRED) {
            const int t = tid;
            const int sidx = t & (step - 1);
            const int m = t / step;
            const int mm1 = (m == 0) ? (M - 1) : (m - 1);
            float x1 = 0.f, x2 = 0.f;
            #pragma unroll
            for (int k = 0; k < 8; ++k) {
                int i1 = m + 3 - k;  if (i1 < 0) i1 += M; else if (i1 >= M) i1 -= M;
                if ((i1 & 1) == 0) {
                    const int pos = i1 * step + sidx;
                    x1 += cur[pos] * REC_LO[k] + cd[pos] * REC_HI[k];
                }
                int i2 = mm1 + 3 - k;  if (i2 < 0) i2 += M; else if (i2 >= M) i2 -= M;
                if ((i2 & 1) == 0) {
                    const int pos = (i2 + 1) * step + sidx;
                    x2 += cur[pos] * REC_LO[k] + cd[pos] * REC_HI[k];
                }
            }
            nxt[t] = 0.5f * (x1 + x2);
        }
        __syncthreads();
        curb ^= 1;
    }

    if (tid < PRED) out[(size_t)row * PRED + tid] = buf[curb][tid];
}

// ======================= launch =======================
extern "C" void kernel_launch(void* const* d_in, const int* in_sizes, int n_in,
                              void* d_out, int out_size, void* d_ws, size_t ws_size,
                              hipStream_t stream) {
    const float* X    = (const float*)d_in[0];   // (224, 49152)
    const float* W    = (const float*)d_in[1];   // (4, 49152, 336)
    const float* bias = (const float*)d_in[2];   // (4, 336)
    float* out        = (float*)d_out;           // (224, 336)
    uint16_t* P       = (uint16_t*)d_ws;                          // 29 MB partials
    uint16_t* Xb      = (uint16_t*)((char*)d_ws + XB_OFFSET);     // 22 MB bf16 X

    cvt_x       <<<5376, 256, 0, stream>>>(X, Xb);
    gemm_partial<<<CTILES * S_CHUNKS, 192, 0, stream>>>(Xb, W, P);
    reduce_iswt <<<M_ROWS, 1024, 0, stream>>>(P, bias, out);
}